// Round 1
// baseline (559.808 us; speedup 1.0000x reference)
//
#include <hip/hip_runtime.h>
#include <hip/hip_bf16.h>

#define DD 64
#define NEG_SLOPE 0.2f

// ---------------------------------------------------------------------------
// h0 = relu(x @ W0 + b0)
// grid-stride, one wave per node, W staged in LDS
// ---------------------------------------------------------------------------
__global__ __launch_bounds__(256) void mm_relu_bias(
    const float* __restrict__ x, const float* __restrict__ W,
    const float* __restrict__ b, float* __restrict__ out, int n_nodes)
{
    __shared__ float Wsh[DD * DD];
    int tid = threadIdx.x;
    for (int i = tid * 4; i < DD * DD; i += 256 * 4)
        *(float4*)&Wsh[i] = *(const float4*)&W[i];
    __syncthreads();

    int lane = tid & 63;
    int wid  = tid >> 6;
    int wgid = blockIdx.x * 4 + wid;
    int stride = gridDim.x * 4;
    float bl = b[lane];
    for (int n = wgid; n < n_nodes; n += stride) {
        float xv = x[n * DD + lane];
        float acc = 0.f;
#pragma unroll
        for (int k = 0; k < DD; ++k)
            acc += __shfl(xv, k) * Wsh[k * DD + lane];
        acc += bl;
        out[n * DD + lane] = acc > 0.f ? acc : 0.f;
    }
}

// ---------------------------------------------------------------------------
// hx = h @ W ; asrc_n = sum(hx*a_src) ; adst_n = sum(hx*a_dst)
// ---------------------------------------------------------------------------
__global__ __launch_bounds__(256) void mm_gat(
    const float* __restrict__ h, const float* __restrict__ W,
    const float* __restrict__ a_src, const float* __restrict__ a_dst,
    float* __restrict__ hx, float* __restrict__ sarr, float* __restrict__ darr,
    int n_nodes)
{
    __shared__ float Wsh[DD * DD];
    int tid = threadIdx.x;
    for (int i = tid * 4; i < DD * DD; i += 256 * 4)
        *(float4*)&Wsh[i] = *(const float4*)&W[i];
    __syncthreads();

    int lane = tid & 63;
    int wid  = tid >> 6;
    int wgid = blockIdx.x * 4 + wid;
    int stride = gridDim.x * 4;
    float as = a_src[lane];
    float ad = a_dst[lane];
    for (int n = wgid; n < n_nodes; n += stride) {
        float xv = h[n * DD + lane];
        float acc = 0.f;
#pragma unroll
        for (int k = 0; k < DD; ++k)
            acc += __shfl(xv, k) * Wsh[k * DD + lane];
        hx[n * DD + lane] = acc;
        float vs = acc * as;
        float vd = acc * ad;
#pragma unroll
        for (int off = 32; off; off >>= 1) {
            vs += __shfl_xor(vs, off);
            vd += __shfl_xor(vd, off);
        }
        if (lane == 0) { sarr[n] = vs; darr[n] = vd; }
    }
}

// ---------------------------------------------------------------------------
// CSR build: histogram of dst, exclusive scan, scatter src into col[]
// ---------------------------------------------------------------------------
__global__ void hist_kernel(const int* __restrict__ dst, int* __restrict__ counts, int E)
{
    int e = blockIdx.x * blockDim.x + threadIdx.x;
    if (e < E) atomicAdd(&counts[dst[e]], 1);
}

__global__ __launch_bounds__(1024) void scan_kernel(
    const int* __restrict__ counts, int* __restrict__ row_ptr,
    int* __restrict__ cursor, int n, int total)
{
    __shared__ int wsum[16];
    __shared__ int carry_sh;
    int tid = threadIdx.x, lane = tid & 63, wid = tid >> 6;
    if (tid == 0) carry_sh = 0;
    __syncthreads();
    for (int base = 0; base < n; base += 1024) {
        int i = base + tid;
        int v = (i < n) ? counts[i] : 0;
        int xi = v;
#pragma unroll
        for (int off = 1; off < 64; off <<= 1) {
            int t = __shfl_up(xi, off);
            if (lane >= off) xi += t;
        }
        if (lane == 63) wsum[wid] = xi;
        __syncthreads();
        if (wid == 0) {
            int w = (lane < 16) ? wsum[lane] : 0;
#pragma unroll
            for (int off = 1; off < 16; off <<= 1) {
                int t = __shfl_up(w, off);
                if (lane >= off) w += t;
            }
            if (lane < 16) wsum[lane] = w;
        }
        __syncthreads();
        int waveoff = (wid == 0) ? 0 : wsum[wid - 1];
        int excl = carry_sh + waveoff + xi - v;
        if (i < n) { row_ptr[i] = excl; cursor[i] = excl; }
        __syncthreads();
        if (tid == 1023) carry_sh += wsum[15];
        __syncthreads();
    }
    if (tid == 0) row_ptr[n] = total;
}

__global__ void scatter_kernel(const int* __restrict__ src, const int* __restrict__ dst,
                               int* __restrict__ cursor, int* __restrict__ col, int E)
{
    int e = blockIdx.x * blockDim.x + threadIdx.x;
    if (e < E) {
        int d = dst[e];
        int pos = atomicAdd(&cursor[d], 1);
        col[pos] = src[e];
    }
}

// ---------------------------------------------------------------------------
// Per-node softmax aggregation + relu + residual (in place on h)
// one wave per node; lanes = features
// ---------------------------------------------------------------------------
__global__ __launch_bounds__(256) void aggregate(
    const float* __restrict__ hx, const int* __restrict__ row_ptr,
    const int* __restrict__ col, const float* __restrict__ sarr,
    const float* __restrict__ darr, const float* __restrict__ bias,
    float* __restrict__ h, int n)
{
    int wgid = (blockIdx.x * blockDim.x + threadIdx.x) >> 6;
    if (wgid >= n) return;
    int lane = threadIdx.x & 63;
    int beg = row_ptr[wgid], end = row_ptr[wgid + 1];
    float adi = darr[wgid];

    // pass 1: group max
    float m = -3.4e38f;
    for (int e = beg + lane; e < end; e += 64) {
        float a = sarr[col[e]] + adi;
        a = a > 0.f ? a : NEG_SLOPE * a;
        m = fmaxf(m, a);
    }
#pragma unroll
    for (int off = 32; off; off >>= 1) m = fmaxf(m, __shfl_xor(m, off));

    // pass 2: sum of exp
    float s = 0.f;
    for (int e = beg + lane; e < end; e += 64) {
        float a = sarr[col[e]] + adi;
        a = a > 0.f ? a : NEG_SLOPE * a;
        s += __expf(a - m);
    }
#pragma unroll
    for (int off = 32; off; off >>= 1) s += __shfl_xor(s, off);
    float inv = (s > 0.f) ? 1.f / s : 0.f;

    // pass 3: weighted feature accumulation (lanes over features)
    float acc = 0.f;
    for (int e = beg; e < end; ++e) {
        int c = col[e];
        float a = sarr[c] + adi;
        a = a > 0.f ? a : NEG_SLOPE * a;
        float w = __expf(a - m) * inv;
        acc += w * hx[c * DD + lane];
    }
    float o = acc + bias[lane];
    o = o > 0.f ? o : 0.f;
    h[wgid * DD + lane] += o;
}

// ---------------------------------------------------------------------------
extern "C" void kernel_launch(void* const* d_in, const int* in_sizes, int n_in,
                              void* d_out, int out_size, void* d_ws, size_t ws_size,
                              hipStream_t stream)
{
    const float* x  = (const float*)d_in[0];
    const int*   ei = (const int*)d_in[1];   // [2,E]: first E = src, next E = dst
    const float* W0 = (const float*)d_in[4];
    const float* b0 = (const float*)d_in[5];
    const float* W1 = (const float*)d_in[6];
    const float* as1= (const float*)d_in[7];
    const float* ad1= (const float*)d_in[8];
    const float* b1 = (const float*)d_in[9];
    const float* W2 = (const float*)d_in[10];
    const float* as2= (const float*)d_in[11];
    const float* ad2= (const float*)d_in[12];
    const float* b2 = (const float*)d_in[13];

    int N = in_sizes[0] / DD;
    int E = in_sizes[1] / 2;
    float* h = (float*)d_out;

    // workspace layout
    float* hx     = (float*)d_ws;              // N*64
    float* sarr   = hx + (size_t)N * DD;       // N
    float* darr   = sarr + N;                  // N
    int*   row_ptr= (int*)(darr + N);          // N+1
    int*   cursor = row_ptr + (N + 1);         // N
    int*   counts = cursor + N;                // N
    int*   colb   = counts + N;                // E

    const int* src = ei;
    const int* dst = ei + E;

    int eblocks = (E + 255) / 256;
    int nblocks_wave = (N + 3) / 4;   // one wave per node, 4 waves/block

    // ---- CSR build (reused by both GAT layers) ----
    hipMemsetAsync(counts, 0, (size_t)N * sizeof(int), stream);
    hist_kernel<<<eblocks, 256, 0, stream>>>(dst, counts, E);
    scan_kernel<<<1, 1024, 0, stream>>>(counts, row_ptr, cursor, N, E);
    scatter_kernel<<<eblocks, 256, 0, stream>>>(src, dst, cursor, colb, E);

    // ---- layer 0: h = relu(x@W0 + b0) ----
    mm_relu_bias<<<512, 256, 0, stream>>>(x, W0, b0, h, N);

    // ---- GAT layer 1 ----
    mm_gat<<<512, 256, 0, stream>>>(h, W1, as1, ad1, hx, sarr, darr, N);
    aggregate<<<nblocks_wave, 256, 0, stream>>>(hx, row_ptr, colb, sarr, darr, b1, h, N);

    // ---- GAT layer 2 ----
    mm_gat<<<512, 256, 0, stream>>>(h, W2, as2, ad2, hx, sarr, darr, N);
    aggregate<<<nblocks_wave, 256, 0, stream>>>(hx, row_ptr, colb, sarr, darr, b2, h, N);
}

// Round 2
// 296.426 us; speedup vs baseline: 1.8885x; 1.8885x over previous
//
#include <hip/hip_runtime.h>
#include <hip/hip_bf16.h>

#define DD 64
#define NEG_SLOPE 0.2f
#define HS 68      // padded LDS stride for h tile (floats)
#define CAP 104    // per-node alpha/col cache capacity in aggregate

// ---------------------------------------------------------------------------
// Tiled matmul: out = relu(x @ W + b). 64-node tile, 4n x float4 register tile
// ---------------------------------------------------------------------------
__global__ __launch_bounds__(256) void mm_relu_bias(
    const float* __restrict__ x, const float* __restrict__ W,
    const float* __restrict__ b, float* __restrict__ out, int n)
{
    __shared__ float Wsh[DD * DD];
    __shared__ float Hsh[DD * HS];
    int tid = threadIdx.x;
    for (int i = tid * 4; i < DD * DD; i += 1024)
        *(float4*)&Wsh[i] = *(const float4*)&W[i];

    int fg = tid & 15;      // feature group: features 4*fg .. 4*fg+3
    int ng = tid >> 4;      // 0..15
    int tile0 = blockIdx.x * 64;
    for (int p = 0; p < 4; ++p) {
        int nl = p * 16 + ng;
        int gn = tile0 + nl;
        if (gn < n)
            *(float4*)&Hsh[nl * HS + 4 * fg] = *(const float4*)&x[gn * DD + 4 * fg];
    }
    __syncthreads();

    float4 acc[4];
#pragma unroll
    for (int j = 0; j < 4; ++j) { acc[j].x = 0.f; acc[j].y = 0.f; acc[j].z = 0.f; acc[j].w = 0.f; }

#pragma unroll 8
    for (int k = 0; k < DD; ++k) {
        float4 w4 = *(float4*)&Wsh[k * DD + 4 * fg];
#pragma unroll
        for (int j = 0; j < 4; ++j) {
            float hv = Hsh[(4 * ng + j) * HS + k];
            acc[j].x += hv * w4.x; acc[j].y += hv * w4.y;
            acc[j].z += hv * w4.z; acc[j].w += hv * w4.w;
        }
    }

    float4 b4 = *(const float4*)&b[4 * fg];
#pragma unroll
    for (int j = 0; j < 4; ++j) {
        int gn = tile0 + 4 * ng + j;
        if (gn < n) {
            float4 o;
            o.x = acc[j].x + b4.x; o.y = acc[j].y + b4.y;
            o.z = acc[j].z + b4.z; o.w = acc[j].w + b4.w;
            o.x = o.x > 0.f ? o.x : 0.f; o.y = o.y > 0.f ? o.y : 0.f;
            o.z = o.z > 0.f ? o.z : 0.f; o.w = o.w > 0.f ? o.w : 0.f;
            *(float4*)&out[gn * DD + 4 * fg] = o;
        }
    }
}

// ---------------------------------------------------------------------------
// hx = h @ W ; sarr = hx.a_src ; darr = hx.a_dst   (same tile structure)
// ---------------------------------------------------------------------------
__global__ __launch_bounds__(256) void mm_gat(
    const float* __restrict__ h, const float* __restrict__ W,
    const float* __restrict__ a_src, const float* __restrict__ a_dst,
    float* __restrict__ hx, float* __restrict__ sarr, float* __restrict__ darr,
    int n)
{
    __shared__ float Wsh[DD * DD];
    __shared__ float Hsh[DD * HS];
    int tid = threadIdx.x;
    for (int i = tid * 4; i < DD * DD; i += 1024)
        *(float4*)&Wsh[i] = *(const float4*)&W[i];

    int fg = tid & 15;
    int ng = tid >> 4;
    int tile0 = blockIdx.x * 64;
    for (int p = 0; p < 4; ++p) {
        int nl = p * 16 + ng;
        int gn = tile0 + nl;
        if (gn < n)
            *(float4*)&Hsh[nl * HS + 4 * fg] = *(const float4*)&h[gn * DD + 4 * fg];
    }
    __syncthreads();

    float4 acc[4];
#pragma unroll
    for (int j = 0; j < 4; ++j) { acc[j].x = 0.f; acc[j].y = 0.f; acc[j].z = 0.f; acc[j].w = 0.f; }

#pragma unroll 8
    for (int k = 0; k < DD; ++k) {
        float4 w4 = *(float4*)&Wsh[k * DD + 4 * fg];
#pragma unroll
        for (int j = 0; j < 4; ++j) {
            float hv = Hsh[(4 * ng + j) * HS + k];
            acc[j].x += hv * w4.x; acc[j].y += hv * w4.y;
            acc[j].z += hv * w4.z; acc[j].w += hv * w4.w;
        }
    }

    float4 as4 = *(const float4*)&a_src[4 * fg];
    float4 ad4 = *(const float4*)&a_dst[4 * fg];
#pragma unroll
    for (int j = 0; j < 4; ++j) {
        int gn = tile0 + 4 * ng + j;
        if (gn < n)
            *(float4*)&hx[gn * DD + 4 * fg] = acc[j];
        float ps = acc[j].x * as4.x + acc[j].y * as4.y + acc[j].z * as4.z + acc[j].w * as4.w;
        float pd = acc[j].x * ad4.x + acc[j].y * ad4.y + acc[j].z * ad4.z + acc[j].w * ad4.w;
#pragma unroll
        for (int off = 8; off; off >>= 1) {
            ps += __shfl_xor(ps, off);
            pd += __shfl_xor(pd, off);
        }
        if (fg == 0 && gn < n) { sarr[gn] = ps; darr[gn] = pd; }
    }
}

// ---------------------------------------------------------------------------
// CSR build: histogram, hierarchical scan (3 kernels), scatter
// ---------------------------------------------------------------------------
__global__ void hist_kernel(const int* __restrict__ dst, int* __restrict__ counts, int E)
{
    int e = blockIdx.x * blockDim.x + threadIdx.x;
    if (e < E) atomicAdd(&counts[dst[e]], 1);
}

__device__ __forceinline__ int wave_incl_scan(int v, int lane)
{
#pragma unroll
    for (int off = 1; off < 64; off <<= 1) {
        int t = __shfl_up(v, off);
        if (lane >= off) v += t;
    }
    return v;
}

__global__ __launch_bounds__(256) void scan_part(
    const int* __restrict__ counts, int* __restrict__ bsum, int n)
{
    __shared__ int wsum[4];
    int tid = threadIdx.x, lane = tid & 63, wid = tid >> 6;
    int i = blockIdx.x * 256 + tid;
    int v = (i < n) ? counts[i] : 0;
#pragma unroll
    for (int off = 32; off; off >>= 1) v += __shfl_xor(v, off);
    if (lane == 0) wsum[wid] = v;
    __syncthreads();
    if (tid == 0) bsum[blockIdx.x] = wsum[0] + wsum[1] + wsum[2] + wsum[3];
}

__global__ __launch_bounds__(256) void scan_top(
    const int* __restrict__ bsum, int* __restrict__ boff, int nb)
{
    __shared__ int wsum[4];
    int tid = threadIdx.x, lane = tid & 63, wid = tid >> 6;
    int v = (tid < nb) ? bsum[tid] : 0;
    int incl = wave_incl_scan(v, lane);
    if (lane == 63) wsum[wid] = incl;
    __syncthreads();
    int wo = 0;
    for (int w = 0; w < wid; ++w) wo += wsum[w];
    if (tid < nb) boff[tid] = wo + incl - v;
}

__global__ __launch_bounds__(256) void scan_final(
    const int* __restrict__ counts, const int* __restrict__ boff,
    int* __restrict__ row_ptr, int* __restrict__ cursor, int n, int total)
{
    __shared__ int wsum[4];
    int tid = threadIdx.x, lane = tid & 63, wid = tid >> 6;
    int i = blockIdx.x * 256 + tid;
    int v = (i < n) ? counts[i] : 0;
    int incl = wave_incl_scan(v, lane);
    if (lane == 63) wsum[wid] = incl;
    __syncthreads();
    int wo = 0;
    for (int w = 0; w < wid; ++w) wo += wsum[w];
    int excl = boff[blockIdx.x] + wo + incl - v;
    if (i < n) { row_ptr[i] = excl; cursor[i] = excl; }
    if (i == 0) row_ptr[n] = total;
}

__global__ void scatter_kernel(const int* __restrict__ src, const int* __restrict__ dst,
                               int* __restrict__ cursor, int* __restrict__ col, int E)
{
    int e = blockIdx.x * blockDim.x + threadIdx.x;
    if (e < E) {
        int d = dst[e];
        int pos = atomicAdd(&cursor[d], 1);
        col[pos] = src[e];
    }
}

// ---------------------------------------------------------------------------
// Softmax aggregation + relu + residual. 16 lanes per node, float4 features.
// alpha & col cached in LDS (wave-synchronous, no barriers needed).
// ---------------------------------------------------------------------------
__global__ __launch_bounds__(256) void aggregate(
    const float4* __restrict__ hx4, const int* __restrict__ row_ptr,
    const int* __restrict__ col, const float* __restrict__ sarr,
    const float* __restrict__ darr, const float* __restrict__ bias,
    float* __restrict__ h, int n)
{
    __shared__ float w_sh[16 * CAP];
    __shared__ int   c_sh[16 * CAP];
    int tid = threadIdx.x;
    int g  = tid >> 4;   // group 0..15 (one node per group)
    int fg = tid & 15;   // lane-in-group: features 4*fg..4*fg+3
    int v = blockIdx.x * 16 + g;
    if (v >= n) return;

    int beg = row_ptr[v], end = row_ptr[v + 1];
    int deg = end - beg;
    float adi = darr[v];
    float* aw = &w_sh[g * CAP];
    int*   ac = &c_sh[g * CAP];

    float4 acc; acc.x = 0.f; acc.y = 0.f; acc.z = 0.f; acc.w = 0.f;
    float m = -3.4e38f, s = 0.f;

    if (deg <= CAP) {
        for (int e = beg + fg; e < end; e += 16) {
            int c = col[e];
            float a = sarr[c] + adi;
            a = a > 0.f ? a : NEG_SLOPE * a;
            int slot = e - beg;
            ac[slot] = c; aw[slot] = a;
            m = fmaxf(m, a);
        }
#pragma unroll
        for (int off = 8; off; off >>= 1) m = fmaxf(m, __shfl_xor(m, off));
        for (int e = beg + fg; e < end; e += 16) {
            int slot = e - beg;
            float w = __expf(aw[slot] - m);
            aw[slot] = w; s += w;
        }
#pragma unroll
        for (int off = 8; off; off >>= 1) s += __shfl_xor(s, off);
#pragma unroll 2
        for (int i = 0; i < deg; ++i) {
            int c = ac[i];
            float w = aw[i];
            float4 hv = hx4[c * 16 + fg];
            acc.x += w * hv.x; acc.y += w * hv.y;
            acc.z += w * hv.z; acc.w += w * hv.w;
        }
    } else {
        // fallback for very high degree (recompute path)
        for (int e = beg + fg; e < end; e += 16) {
            float a = sarr[col[e]] + adi;
            a = a > 0.f ? a : NEG_SLOPE * a;
            m = fmaxf(m, a);
        }
#pragma unroll
        for (int off = 8; off; off >>= 1) m = fmaxf(m, __shfl_xor(m, off));
        for (int e = beg + fg; e < end; e += 16) {
            float a = sarr[col[e]] + adi;
            a = a > 0.f ? a : NEG_SLOPE * a;
            s += __expf(a - m);
        }
#pragma unroll
        for (int off = 8; off; off >>= 1) s += __shfl_xor(s, off);
        for (int e = beg; e < end; ++e) {
            int c = col[e];
            float a = sarr[c] + adi;
            a = a > 0.f ? a : NEG_SLOPE * a;
            float w = __expf(a - m);
            float4 hv = hx4[c * 16 + fg];
            acc.x += w * hv.x; acc.y += w * hv.y;
            acc.z += w * hv.z; acc.w += w * hv.w;
        }
    }

    float inv = (s > 0.f) ? 1.f / s : 0.f;
    float4 b4 = ((const float4*)bias)[fg];
    float4 o;
    o.x = acc.x * inv + b4.x; o.y = acc.y * inv + b4.y;
    o.z = acc.z * inv + b4.z; o.w = acc.w * inv + b4.w;
    o.x = o.x > 0.f ? o.x : 0.f; o.y = o.y > 0.f ? o.y : 0.f;
    o.z = o.z > 0.f ? o.z : 0.f; o.w = o.w > 0.f ? o.w : 0.f;

    float4* hp = (float4*)&h[v * DD + 4 * fg];
    float4 cur = *hp;
    cur.x += o.x; cur.y += o.y; cur.z += o.z; cur.w += o.w;
    *hp = cur;
}

// ---------------------------------------------------------------------------
extern "C" void kernel_launch(void* const* d_in, const int* in_sizes, int n_in,
                              void* d_out, int out_size, void* d_ws, size_t ws_size,
                              hipStream_t stream)
{
    const float* x  = (const float*)d_in[0];
    const int*   ei = (const int*)d_in[1];
    const float* W0 = (const float*)d_in[4];
    const float* b0 = (const float*)d_in[5];
    const float* W1 = (const float*)d_in[6];
    const float* as1= (const float*)d_in[7];
    const float* ad1= (const float*)d_in[8];
    const float* b1 = (const float*)d_in[9];
    const float* W2 = (const float*)d_in[10];
    const float* as2= (const float*)d_in[11];
    const float* ad2= (const float*)d_in[12];
    const float* b2 = (const float*)d_in[13];

    int N = in_sizes[0] / DD;
    int E = in_sizes[1] / 2;
    float* h = (float*)d_out;

    float* hx     = (float*)d_ws;              // N*64
    float* sarr   = hx + (size_t)N * DD;       // N
    float* darr   = sarr + N;                  // N
    int*   row_ptr= (int*)(darr + N);          // N+1
    int*   cursor = row_ptr + (N + 1);         // N
    int*   counts = cursor + N;                // N
    int*   bsum   = counts + N;                // 256
    int*   boff   = bsum + 256;                // 256
    int*   colb   = boff + 256;                // E

    const int* src = ei;
    const int* dst = ei + E;

    int eblocks  = (E + 255) / 256;
    int nb       = (N + 255) / 256;            // scan blocks
    int mm_tiles = (N + 63) / 64;
    int agg_blks = (N + 15) / 16;

    // ---- CSR build ----
    hipMemsetAsync(counts, 0, (size_t)N * sizeof(int), stream);
    hist_kernel<<<eblocks, 256, 0, stream>>>(dst, counts, E);
    scan_part<<<nb, 256, 0, stream>>>(counts, bsum, N);
    scan_top<<<1, 256, 0, stream>>>(bsum, boff, nb);
    scan_final<<<nb, 256, 0, stream>>>(counts, boff, row_ptr, cursor, N, E);
    scatter_kernel<<<eblocks, 256, 0, stream>>>(src, dst, cursor, colb, E);

    // ---- layer 0 ----
    mm_relu_bias<<<mm_tiles, 256, 0, stream>>>(x, W0, b0, h, N);

    // ---- GAT layer 1 ----
    mm_gat<<<mm_tiles, 256, 0, stream>>>(h, W1, as1, ad1, hx, sarr, darr, N);
    aggregate<<<agg_blks, 256, 0, stream>>>((const float4*)hx, row_ptr, colb, sarr, darr, b1, h, N);

    // ---- GAT layer 2 ----
    mm_gat<<<mm_tiles, 256, 0, stream>>>(h, W2, as2, ad2, hx, sarr, darr, N);
    aggregate<<<agg_blks, 256, 0, stream>>>((const float4*)hx, row_ptr, colb, sarr, darr, b2, h, N);
}